// Round 7
// baseline (391.179 us; speedup 1.0000x reference)
//
#include <hip/hip_runtime.h>

// ---- problem constants ----
#define B_    2
#define N_    2049
#define NPAD  2112          // keys padded to multiple of 64
#define D_    1024
#define H_    16
#define DH    64
#define MROWS (B_ * N_)     // 4098
#define MPAD  4224          // MROWS padded to multiple of 128 (GEMM block tile)

using bf16x8 = __attribute__((ext_vector_type(8))) short;
using f32x4  = __attribute__((ext_vector_type(4))) float;

#define AS1 __attribute__((address_space(1)))
#define AS3 __attribute__((address_space(3)))

__device__ __forceinline__ float bf2f(short s) {
  union { unsigned u; float f; } a; a.u = ((unsigned)(unsigned short)s) << 16; return a.f;
}
__device__ __forceinline__ short f2bf(float f) {
  union { float f; unsigned u; } a; a.f = f;
  unsigned r = a.u + 0x7fffu + ((a.u >> 16) & 1u);   // round-to-nearest-even
  return (short)(r >> 16);
}
// truncation pack of two fp32 -> bf16x2
__device__ __forceinline__ unsigned pack_trunc(float lo, float hi) {
  union { float f; unsigned u; } a, b; a.f = lo; b.f = hi;
  return (b.u & 0xffff0000u) | (a.u >> 16);
}
// async global->LDS DMA, 16 B/lane; LDS dst is wave-uniform base (+lane*16 by HW)
__device__ __forceinline__ void dma16(const short* g, AS3 short* l) {
  __builtin_amdgcn_global_load_lds((const AS1 unsigned*)g, (AS3 unsigned*)l, 16, 0, 0);
}

// ---------------- LayerNorm: fp32 in -> bf16 out ----------------
__global__ __launch_bounds__(256) void ln_kernel(const float* __restrict__ x,
                                                 const float* __restrict__ gamma,
                                                 const float* __restrict__ beta,
                                                 short* __restrict__ xn) {
  int row = blockIdx.x;
  int tid = threadIdx.x;
  const float4 v = ((const float4*)(x + (size_t)row * D_))[tid];
  float s  = v.x + v.y + v.z + v.w;
  float ss = v.x * v.x + v.y * v.y + v.z * v.z + v.w * v.w;
  for (int o = 1; o < 64; o <<= 1) { s += __shfl_xor(s, o, 64); ss += __shfl_xor(ss, o, 64); }
  __shared__ float sb[4], s2b[4];
  int wid = tid >> 6;
  if ((tid & 63) == 0) { sb[wid] = s; s2b[wid] = ss; }
  __syncthreads();
  float st  = sb[0] + sb[1] + sb[2] + sb[3];
  float sst = s2b[0] + s2b[1] + s2b[2] + s2b[3];
  float mu  = st * (1.0f / D_);
  float var = sst * (1.0f / D_) - mu * mu;
  float rs  = rsqrtf(var + 1e-5f);
  const float4 g  = ((const float4*)gamma)[tid];
  const float4 be = ((const float4*)beta)[tid];
  short4 o4;
  o4.x = f2bf((v.x - mu) * rs * g.x + be.x);
  o4.y = f2bf((v.y - mu) * rs * g.y + be.y);
  o4.z = f2bf((v.z - mu) * rs * g.z + be.z);
  o4.w = f2bf((v.w - mu) * rs * g.w + be.w);
  ((short4*)(xn + (size_t)row * D_))[tid] = o4;
}

// ------------- transpose+cast: fp32 [K][Nn] -> bf16 [Nn][K] -------------
__global__ __launch_bounds__(256) void transpose_cast(const float* __restrict__ in,
                                                      short* __restrict__ out,
                                                      int K, int Nn) {
  int idx = blockIdx.x * 256 + threadIdx.x;
  if (idx >= K * Nn) return;
  int kk = idx / Nn, nn = idx - kk * Nn;
  out[(size_t)nn * K + kk] = f2bf(in[idx]);
}

// ------------- m97-style 128x128 GEMM: C[M][Ncols] = A[M][K] * BT[Ncols][K]^T -------------
#define BM 128
#define BK 32
template <typename OutT>
__global__ __launch_bounds__(256) void gemm128(const short* __restrict__ A,
                                               const short* __restrict__ BT,
                                               OutT* __restrict__ C,
                                               int Mstore, int Ncols, int K) {
  int lane = threadIdx.x & 63, wid = threadIdx.x >> 6;
  int quad = lane >> 4, l16 = lane & 15;
  int wr = wid >> 1, wc = wid & 1;
  int m0 = blockIdx.x * BM;
  int n0 = blockIdx.y * BM;

  __shared__ __align__(16) short Abuf[2][BM * BK];   // [row][k] row-major, 8 KB each
  __shared__ __align__(16) short Bbuf[2][BM * BK];
  AS3 short* AbufL = (AS3 short*)&Abuf[0][0];
  AS3 short* BbufL = (AS3 short*)&Bbuf[0][0];

  f32x4 acc[4][4] = {};

  int lrow = lane >> 2, lcol8 = (lane & 3) * 8;
  const short* Ag = A  + (size_t)(m0 + lrow) * K + lcol8;
  const short* Bg = BT + (size_t)(n0 + lrow) * K + lcol8;

  auto stage = [&](int kt, int bb) {
    int k0 = kt * BK;
    #pragma unroll
    for (int i = 0; i < 2; ++i) {
      int j = wid * 2 + i;                  // slab 0..7 (16 rows each)
      dma16(Ag + (size_t)j * 16 * K + k0, AbufL + bb * (BM * BK) + j * 512);
      dma16(Bg + (size_t)j * 16 * K + k0, BbufL + bb * (BM * BK) + j * 512);
    }
  };

  stage(0, 0);
  __syncthreads();

  int KT = K / BK;
  for (int kt = 0; kt < KT; ++kt) {
    int cur = kt & 1;
    if (kt + 1 < KT) stage(kt + 1, cur ^ 1);
    const short* Ab = &Abuf[cur][0];
    const short* Bb = &Bbuf[cur][0];
    bf16x8 af[4], bfr[4];
    #pragma unroll
    for (int s = 0; s < 4; ++s)
      af[s] = *(const bf16x8*)&Ab[(wr * 64 + s * 16 + l16) * BK + quad * 8];
    #pragma unroll
    for (int t = 0; t < 4; ++t)
      bfr[t] = *(const bf16x8*)&Bb[(wc * 64 + t * 16 + l16) * BK + quad * 8];
    #pragma unroll
    for (int s = 0; s < 4; ++s)
      #pragma unroll
      for (int t = 0; t < 4; ++t)
        acc[s][t] = __builtin_amdgcn_mfma_f32_16x16x32_bf16(af[s], bfr[t], acc[s][t], 0, 0, 0);
    __syncthreads();
  }

  #pragma unroll
  for (int s = 0; s < 4; ++s)
    #pragma unroll
    for (int r = 0; r < 4; ++r) {
      int row = m0 + wr * 64 + s * 16 + quad * 4 + r;
      if (row < Mstore) {
        size_t rb = (size_t)row * Ncols + n0 + wc * 64;
        #pragma unroll
        for (int t = 0; t < 4; ++t) {
          float val = acc[s][t][r];
          if constexpr (sizeof(OutT) == 2)
            C[rb + t * 16 + l16] = (OutT)(unsigned short)f2bf(val);
          else
            C[rb + t * 16 + l16] = (OutT)val;
        }
      }
    }
}

// ------------- RoPE + head reshape: qkv[.][3072] -> q,k [B][H][NPAD][64], vT [B][H][64][NPAD] -------------
__global__ __launch_bounds__(256) void rope_kernel(const short* __restrict__ qkv,
                                                   short* __restrict__ qg,
                                                   short* __restrict__ kg,
                                                   short* __restrict__ vT) {
  int idx = blockIdx.x * 256 + threadIdx.x;
  const int total = B_ * H_ * NPAD * 32;
  if (idx >= total) return;
  int i = idx & 31;
  int t = idx >> 5;
  int n = t % NPAD; t /= NPAD;
  int h = t & (H_ - 1); int b = t >> 4;
  size_t hb = ((size_t)(b * H_ + h)) * NPAD * DH;
  size_t ob = hb + (size_t)n * DH;
  if (n >= N_) {
    qg[ob + i] = 0; qg[ob + i + 32] = 0;
    kg[ob + i] = 0; kg[ob + i + 32] = 0;
    vT[hb + (size_t)i * NPAD + n] = 0;
    vT[hb + (size_t)(i + 32) * NPAD + n] = 0;
    return;
  }
  size_t ib = ((size_t)(b * N_ + n)) * 3072 + h * DH;
  float q1 = bf2f(qkv[ib + i]),        q2 = bf2f(qkv[ib + i + 32]);
  float k1 = bf2f(qkv[ib + 1024 + i]), k2 = bf2f(qkv[ib + 1024 + i + 32]);
  float v1 = bf2f(qkv[ib + 2048 + i]), v2 = bf2f(qkv[ib + 2048 + i + 32]);
  if (n > 0) {
    float ang = (float)(n - 1) * powf(10000.0f, -(float)i * (1.0f / 32.0f));
    float sn, cs; sincosf(ang, &sn, &cs);
    float nq1 = q1 * cs - q2 * sn, nq2 = q2 * cs + q1 * sn;
    float nk1 = k1 * cs - k2 * sn, nk2 = k2 * cs + k1 * sn;
    q1 = nq1; q2 = nq2; k1 = nk1; k2 = nk2;
  }
  qg[ob + i] = f2bf(q1 * 0.125f); qg[ob + i + 32] = f2bf(q2 * 0.125f);  // SCALE folded into q
  kg[ob + i] = f2bf(k1); kg[ob + i + 32] = f2bf(k2);
  vT[hb + (size_t)i * NPAD + n] = f2bf(v1);
  vT[hb + (size_t)(i + 32) * NPAD + n] = f2bf(v2);
}

// ------------- flash attention v3: wave=16q, wg=64q, XCD-clustered grid -------------
// S^T = K*Q^T (C-layout), P^T->B-layout via wave-private padded LDS, O^T = V^T*P^T.
// K-tile (8 KB) DMA double-buffered, shared by 4 waves. 1056 wg; blocks decoded so
// each XCD owns 4 heads x 33 q-blocks -> head K/V stays L2-resident (4 heads ~2.1MB).
struct VTile { bf16x8 f[8]; };
__device__ __forceinline__ void load_vtile(const short* vbase, int k0, int l16, int quad, VTile& t) {
  #pragma unroll
  for (int c = 0; c < 2; ++c)
    #pragma unroll
    for (int d = 0; d < 4; ++d) {
      const short* p = vbase + (size_t)(d * 16 + l16) * NPAD + k0 + c * 32 + quad * 8;
      t.f[c * 4 + d] = *(const bf16x8*)p;
    }
}

#define PSTRIDE 72   // 64 + 8: pads P rows so LDS accesses stay <=2-way (free)

__global__ __launch_bounds__(256) void attn_kernel(const short* __restrict__ qg,
                                                   const short* __restrict__ kg,
                                                   const short* __restrict__ vT,
                                                   short* __restrict__ attn_out) {
  // XCD-clustered decode (heuristic: wg->XCD is round-robin on blockIdx)
  int blk = blockIdx.x;             // 0..1055
  int xcd = blk & 7;
  int t_  = blk >> 3;               // 0..131
  int bh  = xcd * 4 + (t_ & 3);     // 0..31
  int qblk = t_ >> 2;               // 0..32
  int b = bh >> 4, h = bh & 15;

  int lane = threadIdx.x & 63, wid = threadIdx.x >> 6;
  int quad = lane >> 4, l16 = lane & 15;
  int q0 = qblk * 64 + wid * 16;    // this wave's 16 query rows
  size_t hb = (size_t)bh * NPAD * DH;
  const short* kg_hb = kg + hb;
  const short* vT_hb = vT + hb;

  __shared__ __align__(16) short Kbuf[2][8 * 512];       // 16 KB
  __shared__ __align__(16) short Pbuf[4][16 * PSTRIDE];  // 9.2 KB, wave-private
  AS3 short* KbufL = (AS3 short*)&Kbuf[0][0];
  short* Pw = &Pbuf[wid][0];

  // Q B-frag (16 queries): lane holds Q[q0+l16][dh=quad*8+j]
  const short* qp = qg + hb + (size_t)(q0 + l16) * DH;
  bf16x8 bq0 = *(const bf16x8*)(qp + quad * 8);
  bf16x8 bq1 = *(const bf16x8*)(qp + 32 + quad * 8);

  f32x4 o[4] = {};          // O^T[dh=d*16+quad*4+r][q=l16]
  float lrun = 0.0f;

  auto stage = [&](int kt, int bb) {
    int k0 = kt * 64;
    #pragma unroll
    for (int i = 0; i < 2; ++i) {
      int j = wid * 2 + i;
      int t = j >> 1, half = j & 1;
      const short* g = kg_hb + (size_t)(k0 + t * 16 + l16) * DH + half * 32 + quad * 8;
      dma16(g, KbufL + bb * 4096 + j * 512);
    }
  };

  stage(0, 0);
  __syncthreads();

  for (int kt = 0; kt <= 32; ++kt) {
    int cur = kt & 1;
    if (kt < 32) stage(kt + 1, cur ^ 1);
    int k0 = kt * 64;
    VTile v;                          // V loads early (hidden by QK+softmax)
    load_vtile(vT_hb, k0, l16, quad, v);

    // ---- S^T = K * Q^T ----
    const short* Kc = &Kbuf[cur][0];
    f32x4 s[4] = {};
    #pragma unroll
    for (int t = 0; t < 4; ++t) {
      bf16x8 kf0 = *(const bf16x8*)&Kc[(t * 2 + 0) * 512 + lane * 8];
      bf16x8 kf1 = *(const bf16x8*)&Kc[(t * 2 + 1) * 512 + lane * 8];
      s[t] = __builtin_amdgcn_mfma_f32_16x16x32_bf16(kf0, bq0, s[t], 0, 0, 0);
      s[t] = __builtin_amdgcn_mfma_f32_16x16x32_bf16(kf1, bq1, s[t], 0, 0, 0);
    }
    // mask invalid keys (only final tile; wave-uniform branch)
    if (k0 + 64 > N_) {
      #pragma unroll
      for (int t = 0; t < 4; ++t)
        #pragma unroll
        for (int r = 0; r < 4; ++r)
          if (k0 + t * 16 + quad * 4 + r >= N_) s[t][r] = -1e30f;
    }
    // ---- p = exp(s), pack to P LDS ([q][key], padded), row-sum ----
    {
      float vsum = 0.0f;
      int prow = l16 * PSTRIDE;
      #pragma unroll
      for (int t = 0; t < 4; ++t) {
        float p0 = __expf(s[t][0]), p1 = __expf(s[t][1]);
        float p2 = __expf(s[t][2]), p3 = __expf(s[t][3]);
        vsum += (p0 + p1) + (p2 + p3);
        *(unsigned*)&Pw[prow + t * 16 + quad * 4]     = pack_trunc(p0, p1);
        *(unsigned*)&Pw[prow + t * 16 + quad * 4 + 2] = pack_trunc(p2, p3);
      }
      vsum += __shfl_xor(vsum, 16, 64);
      vsum += __shfl_xor(vsum, 32, 64);
      lrun += vsum;
    }
    // ---- O^T += V^T * P^T (B-frags from wave-private LDS, no barrier) ----
    #pragma unroll
    for (int c = 0; c < 2; ++c) {
      bf16x8 bp = *(const bf16x8*)&Pw[l16 * PSTRIDE + c * 32 + quad * 8];
      #pragma unroll
      for (int d = 0; d < 4; ++d)
        o[d] = __builtin_amdgcn_mfma_f32_16x16x32_bf16(v.f[c * 4 + d], bp, o[d], 0, 0, 0);
    }
    __syncthreads();   // DMA kt+1 complete; all waves done with Kbuf[cur]
  }

  // epilogue: O^T / l -> attn_out[B*N][1024]
  float inv = 1.0f / lrun;
  int qrow = q0 + l16;
  if (qrow < N_) {
    size_t rowb = (size_t)(b * N_ + qrow) * (H_ * DH) + h * DH;
    #pragma unroll
    for (int d = 0; d < 4; ++d) {
      short4 st;
      st.x = f2bf(o[d][0] * inv);
      st.y = f2bf(o[d][1] * inv);
      st.z = f2bf(o[d][2] * inv);
      st.w = f2bf(o[d][3] * inv);
      *(short4*)(attn_out + rowb + d * 16 + quad * 4) = st;
    }
  }
}

// ---------------- launcher ----------------
extern "C" void kernel_launch(void* const* d_in, const int* in_sizes, int n_in,
                              void* d_out, int out_size, void* d_ws, size_t ws_size,
                              hipStream_t stream) {
  const float* x     = (const float*)d_in[0];
  const float* gamma = (const float*)d_in[1];
  const float* beta  = (const float*)d_in[2];
  const float* w_qkv = (const float*)d_in[3];
  const float* w_out = (const float*)d_in[4];

  short* wqkvT = (short*)d_ws;                         // [3072][1024]
  short* woutT = wqkvT + (size_t)3072 * 1024;          // [1024][1024]
  short* xn    = woutT + (size_t)1024 * 1024;          // [4224][1024] (aliased as attn_out later)
  short* qkv   = xn    + (size_t)MPAD * 1024;          // [4224][3072]
  short* qg    = qkv   + (size_t)MPAD * 3072;          // [2][16][2112][64]
  short* kg    = qg    + (size_t)B_ * H_ * NPAD * DH;
  short* vTg   = kg    + (size_t)B_ * H_ * NPAD * DH;  // [2][16][64][2112]
  short* attn_out = xn;

  ln_kernel<<<MROWS, 256, 0, stream>>>(x, gamma, beta, xn);
  transpose_cast<<<(1024 * 3072 + 255) / 256, 256, 0, stream>>>(w_qkv, wqkvT, 1024, 3072);
  transpose_cast<<<(1024 * 1024 + 255) / 256, 256, 0, stream>>>(w_out, woutT, 1024, 1024);
  {
    dim3 g(MPAD / 128, 3072 / 128);        // 33 x 24
    gemm128<unsigned short><<<g, 256, 0, stream>>>(xn, wqkvT, (unsigned short*)qkv, MROWS, 3072, 1024);
  }
  rope_kernel<<<(B_ * H_ * NPAD * 32 + 255) / 256, 256, 0, stream>>>(qkv, qg, kg, vTg);
  {
    attn_kernel<<<33 * 32, 256, 0, stream>>>(qg, kg, vTg, attn_out);  // XCD-clustered 1-D grid
  }
  {
    dim3 g(MPAD / 128, 1024 / 128);        // 33 x 8
    gemm128<float><<<g, 256, 0, stream>>>(attn_out, woutT, (float*)d_out, MROWS, 1024, 1024);
  }
}

// Round 8
// 305.797 us; speedup vs baseline: 1.2792x; 1.2792x over previous
//
#include <hip/hip_runtime.h>

// ---- problem constants ----
#define B_    2
#define N_    2049
#define NPAD  2112          // keys padded to multiple of 64
#define D_    1024
#define H_    16
#define DH    64
#define MROWS (B_ * N_)     // 4098
#define MPAD  4224          // MROWS padded to multiple of 128 (GEMM block tile)

using bf16x8 = __attribute__((ext_vector_type(8))) short;
using f32x4  = __attribute__((ext_vector_type(4))) float;

#define AS1 __attribute__((address_space(1)))
#define AS3 __attribute__((address_space(3)))

__device__ __forceinline__ float bf2f(short s) {
  union { unsigned u; float f; } a; a.u = ((unsigned)(unsigned short)s) << 16; return a.f;
}
__device__ __forceinline__ short f2bf(float f) {
  union { float f; unsigned u; } a; a.f = f;
  unsigned r = a.u + 0x7fffu + ((a.u >> 16) & 1u);   // round-to-nearest-even
  return (short)(r >> 16);
}
// truncation pack of two fp32 -> bf16x2
__device__ __forceinline__ unsigned pack_trunc(float lo, float hi) {
  union { float f; unsigned u; } a, b; a.f = lo; b.f = hi;
  return (b.u & 0xffff0000u) | (a.u >> 16);
}
// async global->LDS DMA, 16 B/lane; LDS dst is wave-uniform base (+lane*16 by HW)
__device__ __forceinline__ void dma16(const short* g, AS3 short* l) {
  __builtin_amdgcn_global_load_lds((const AS1 unsigned*)g, (AS3 unsigned*)l, 16, 0, 0);
}

// ---------------- LayerNorm: fp32 in -> bf16 out ----------------
__global__ __launch_bounds__(256) void ln_kernel(const float* __restrict__ x,
                                                 const float* __restrict__ gamma,
                                                 const float* __restrict__ beta,
                                                 short* __restrict__ xn) {
  int row = blockIdx.x;
  int tid = threadIdx.x;
  const float4 v = ((const float4*)(x + (size_t)row * D_))[tid];
  float s  = v.x + v.y + v.z + v.w;
  float ss = v.x * v.x + v.y * v.y + v.z * v.z + v.w * v.w;
  for (int o = 1; o < 64; o <<= 1) { s += __shfl_xor(s, o, 64); ss += __shfl_xor(ss, o, 64); }
  __shared__ float sb[4], s2b[4];
  int wid = tid >> 6;
  if ((tid & 63) == 0) { sb[wid] = s; s2b[wid] = ss; }
  __syncthreads();
  float st  = sb[0] + sb[1] + sb[2] + sb[3];
  float sst = s2b[0] + s2b[1] + s2b[2] + s2b[3];
  float mu  = st * (1.0f / D_);
  float var = sst * (1.0f / D_) - mu * mu;
  float rs  = rsqrtf(var + 1e-5f);
  const float4 g  = ((const float4*)gamma)[tid];
  const float4 be = ((const float4*)beta)[tid];
  short4 o4;
  o4.x = f2bf((v.x - mu) * rs * g.x + be.x);
  o4.y = f2bf((v.y - mu) * rs * g.y + be.y);
  o4.z = f2bf((v.z - mu) * rs * g.z + be.z);
  o4.w = f2bf((v.w - mu) * rs * g.w + be.w);
  ((short4*)(xn + (size_t)row * D_))[tid] = o4;
}

// ------------- transpose+cast: fp32 [K][Nn] -> bf16 [Nn][K] -------------
__global__ __launch_bounds__(256) void transpose_cast(const float* __restrict__ in,
                                                      short* __restrict__ out,
                                                      int K, int Nn) {
  int idx = blockIdx.x * 256 + threadIdx.x;
  if (idx >= K * Nn) return;
  int kk = idx / Nn, nn = idx - kk * Nn;
  out[(size_t)nn * K + kk] = f2bf(in[idx]);
}

// ------------- m97-style 128x128 GEMM: C[M][Ncols] = A[M][K] * BT[Ncols][K]^T -------------
#define BM 128
#define BK 32
template <typename OutT>
__global__ __launch_bounds__(256) void gemm128(const short* __restrict__ A,
                                               const short* __restrict__ BT,
                                               OutT* __restrict__ C,
                                               int Mstore, int Ncols, int K) {
  int lane = threadIdx.x & 63, wid = threadIdx.x >> 6;
  int quad = lane >> 4, l16 = lane & 15;
  int wr = wid >> 1, wc = wid & 1;
  int m0 = blockIdx.x * BM;
  int n0 = blockIdx.y * BM;

  __shared__ __align__(16) short Abuf[2][BM * BK];   // [row][k] row-major, 8 KB each
  __shared__ __align__(16) short Bbuf[2][BM * BK];
  AS3 short* AbufL = (AS3 short*)&Abuf[0][0];
  AS3 short* BbufL = (AS3 short*)&Bbuf[0][0];

  f32x4 acc[4][4] = {};

  int lrow = lane >> 2, lcol8 = (lane & 3) * 8;
  const short* Ag = A  + (size_t)(m0 + lrow) * K + lcol8;
  const short* Bg = BT + (size_t)(n0 + lrow) * K + lcol8;

  auto stage = [&](int kt, int bb) {
    int k0 = kt * BK;
    #pragma unroll
    for (int i = 0; i < 2; ++i) {
      int j = wid * 2 + i;                  // slab 0..7 (16 rows each)
      dma16(Ag + (size_t)j * 16 * K + k0, AbufL + bb * (BM * BK) + j * 512);
      dma16(Bg + (size_t)j * 16 * K + k0, BbufL + bb * (BM * BK) + j * 512);
    }
  };

  stage(0, 0);
  __syncthreads();

  int KT = K / BK;
  for (int kt = 0; kt < KT; ++kt) {
    int cur = kt & 1;
    if (kt + 1 < KT) stage(kt + 1, cur ^ 1);
    const short* Ab = &Abuf[cur][0];
    const short* Bb = &Bbuf[cur][0];
    bf16x8 af[4], bfr[4];
    #pragma unroll
    for (int s = 0; s < 4; ++s)
      af[s] = *(const bf16x8*)&Ab[(wr * 64 + s * 16 + l16) * BK + quad * 8];
    #pragma unroll
    for (int t = 0; t < 4; ++t)
      bfr[t] = *(const bf16x8*)&Bb[(wc * 64 + t * 16 + l16) * BK + quad * 8];
    #pragma unroll
    for (int s = 0; s < 4; ++s)
      #pragma unroll
      for (int t = 0; t < 4; ++t)
        acc[s][t] = __builtin_amdgcn_mfma_f32_16x16x32_bf16(af[s], bfr[t], acc[s][t], 0, 0, 0);
    __syncthreads();
  }

  #pragma unroll
  for (int s = 0; s < 4; ++s)
    #pragma unroll
    for (int r = 0; r < 4; ++r) {
      int row = m0 + wr * 64 + s * 16 + quad * 4 + r;
      if (row < Mstore) {
        size_t rb = (size_t)row * Ncols + n0 + wc * 64;
        #pragma unroll
        for (int t = 0; t < 4; ++t) {
          float val = acc[s][t][r];
          if constexpr (sizeof(OutT) == 2)
            C[rb + t * 16 + l16] = (OutT)(unsigned short)f2bf(val);
          else
            C[rb + t * 16 + l16] = (OutT)val;
        }
      }
    }
}

// ------------- RoPE + head reshape: qkv[.][3072] -> q,k [B][H][NPAD][64], vT [B][H][64][NPAD] -------------
__global__ __launch_bounds__(256) void rope_kernel(const short* __restrict__ qkv,
                                                   short* __restrict__ qg,
                                                   short* __restrict__ kg,
                                                   short* __restrict__ vT) {
  int idx = blockIdx.x * 256 + threadIdx.x;
  const int total = B_ * H_ * NPAD * 32;
  if (idx >= total) return;
  int i = idx & 31;
  int t = idx >> 5;
  int n = t % NPAD; t /= NPAD;
  int h = t & (H_ - 1); int b = t >> 4;
  size_t hb = ((size_t)(b * H_ + h)) * NPAD * DH;
  size_t ob = hb + (size_t)n * DH;
  if (n >= N_) {
    qg[ob + i] = 0; qg[ob + i + 32] = 0;
    kg[ob + i] = 0; kg[ob + i + 32] = 0;
    vT[hb + (size_t)i * NPAD + n] = 0;
    vT[hb + (size_t)(i + 32) * NPAD + n] = 0;
    return;
  }
  size_t ib = ((size_t)(b * N_ + n)) * 3072 + h * DH;
  float q1 = bf2f(qkv[ib + i]),        q2 = bf2f(qkv[ib + i + 32]);
  float k1 = bf2f(qkv[ib + 1024 + i]), k2 = bf2f(qkv[ib + 1024 + i + 32]);
  float v1 = bf2f(qkv[ib + 2048 + i]), v2 = bf2f(qkv[ib + 2048 + i + 32]);
  if (n > 0) {
    float ang = (float)(n - 1) * powf(10000.0f, -(float)i * (1.0f / 32.0f));
    float sn, cs; sincosf(ang, &sn, &cs);
    float nq1 = q1 * cs - q2 * sn, nq2 = q2 * cs + q1 * sn;
    float nk1 = k1 * cs - k2 * sn, nk2 = k2 * cs + k1 * sn;
    q1 = nq1; q2 = nq2; k1 = nk1; k2 = nk2;
  }
  qg[ob + i] = f2bf(q1 * 0.125f); qg[ob + i + 32] = f2bf(q2 * 0.125f);  // SCALE folded into q
  kg[ob + i] = f2bf(k1); kg[ob + i + 32] = f2bf(k2);
  vT[hb + (size_t)i * NPAD + n] = f2bf(v1);
  vT[hb + (size_t)(i + 32) * NPAD + n] = f2bf(v2);
}

// ------------- flash attention v4: r6 tile (wave=32q) + K-split(2) + XCD clustering -------------
// Fixed-max softmax => partial (O,l) over disjoint key halves are directly addable.
// Each wg: 128 queries x half the key tiles; writes unnormalized O (bf16) + l (fp32).
// 1088 wg = 8 XCD x 4 heads x 17 qblk x 2 ksplit; per-XCD K/V footprint 2.2 MB (L2-resident).
struct VTile { bf16x8 f[8]; };
__device__ __forceinline__ void load_vtile(const short* vbase, int k0, int l16, int quad, VTile& t) {
  #pragma unroll
  for (int c = 0; c < 2; ++c)
    #pragma unroll
    for (int d = 0; d < 4; ++d) {
      const short* p = vbase + (size_t)(d * 16 + l16) * NPAD + k0 + c * 32 + quad * 8;
      t.f[c * 4 + d] = *(const bf16x8*)p;
    }
}

#define PSTRIDE 72   // 64 + 8: pads P rows so LDS accesses stay <=2-way (free)

__global__ __launch_bounds__(256, 2) void attn_kernel(const short* __restrict__ qg,
                                                      const short* __restrict__ kg,
                                                      const short* __restrict__ vT,
                                                      short* __restrict__ Opart,
                                                      float* __restrict__ lpart) {
  // XCD-clustered decode: blk&7 -> XCD (round-robin heuristic)
  int blk = blockIdx.x;             // 0..1087
  int xcd = blk & 7;
  int t_  = blk >> 3;               // 0..135
  int bh  = xcd * 4 + (t_ & 3);     // 4 heads per XCD
  int u   = t_ >> 2;                // 0..33
  int ks  = (u >= 17) ? 1 : 0;
  int qblk = u - ks * 17;           // 0..16
  int kt0 = ks * 17, kt1 = ks ? 32 : 16;   // inclusive key-tile range
  int b = bh >> 4, h = bh & 15;
  (void)b; (void)h;

  int lane = threadIdx.x & 63, wid = threadIdx.x >> 6;
  int quad = lane >> 4, l16 = lane & 15;
  int q0 = qblk * 128 + wid * 32;          // this wave's 32 query rows
  size_t hb = (size_t)bh * NPAD * DH;
  const short* kg_hb = kg + hb;
  const short* vT_hb = vT + hb;

  __shared__ __align__(16) short Kbuf[2][8 * 512];       // 16 KB
  __shared__ __align__(16) short Pbuf[4][32 * PSTRIDE];  // 18.4 KB, wave-private
  AS3 short* KbufL = (AS3 short*)&Kbuf[0][0];
  short* Pw = &Pbuf[wid][0];

  int qr0 = q0 + l16;      if (qr0 >= NPAD) qr0 = 0;   // clamp; never stored
  int qr1 = q0 + 16 + l16; if (qr1 >= NPAD) qr1 = 0;
  const short* qp0 = qg + hb + (size_t)qr0 * DH;
  const short* qp1 = qg + hb + (size_t)qr1 * DH;
  bf16x8 bq0 = *(const bf16x8*)(qp0 + quad * 8);
  bf16x8 bq1 = *(const bf16x8*)(qp0 + 32 + quad * 8);
  bf16x8 cq0 = *(const bf16x8*)(qp1 + quad * 8);
  bf16x8 cq1 = *(const bf16x8*)(qp1 + 32 + quad * 8);

  f32x4 o[2][4] = {};       // O^T[dh=d*16+quad*4+r][q = q0+qs*16+l16]
  float lrun[2] = {0.0f, 0.0f};

  auto stage = [&](int kt, int bb) {
    int k0 = kt * 64;
    #pragma unroll
    for (int i = 0; i < 2; ++i) {
      int j = wid * 2 + i;
      int t = j >> 1, half = j & 1;
      const short* g = kg_hb + (size_t)(k0 + t * 16 + l16) * DH + half * 32 + quad * 8;
      dma16(g, KbufL + bb * 4096 + j * 512);
    }
  };

  stage(kt0, 0);
  __syncthreads();

  for (int kt = kt0; kt <= kt1; ++kt) {
    int cur = (kt - kt0) & 1;
    if (kt < kt1) stage(kt + 1, cur ^ 1);
    int k0 = kt * 64;
    VTile v;                                // V loads early (hidden by QK+softmax)
    load_vtile(vT_hb, k0, l16, quad, v);

    // ---- S^T = K * Q^T ----
    const short* Kc = &Kbuf[cur][0];
    f32x4 s[2][4] = {};
    #pragma unroll
    for (int t = 0; t < 4; ++t) {
      bf16x8 kf0 = *(const bf16x8*)&Kc[(t * 2 + 0) * 512 + lane * 8];
      bf16x8 kf1 = *(const bf16x8*)&Kc[(t * 2 + 1) * 512 + lane * 8];
      s[0][t] = __builtin_amdgcn_mfma_f32_16x16x32_bf16(kf0, bq0, s[0][t], 0, 0, 0);
      s[0][t] = __builtin_amdgcn_mfma_f32_16x16x32_bf16(kf1, bq1, s[0][t], 0, 0, 0);
      s[1][t] = __builtin_amdgcn_mfma_f32_16x16x32_bf16(kf0, cq0, s[1][t], 0, 0, 0);
      s[1][t] = __builtin_amdgcn_mfma_f32_16x16x32_bf16(kf1, cq1, s[1][t], 0, 0, 0);
    }
    // mask invalid keys (only final tile; wave-uniform branch)
    if (k0 + 64 > N_) {
      #pragma unroll
      for (int qs = 0; qs < 2; ++qs)
        #pragma unroll
        for (int t = 0; t < 4; ++t)
          #pragma unroll
          for (int r = 0; r < 4; ++r)
            if (k0 + t * 16 + quad * 4 + r >= N_) s[qs][t][r] = -1e30f;
    }
    // ---- p = exp(s) (fixed-max softmax), pack to wave-private LDS, row-sum ----
    #pragma unroll
    for (int qs = 0; qs < 2; ++qs) {
      float vsum = 0.0f;
      int prow = (qs * 16 + l16) * PSTRIDE;
      #pragma unroll
      for (int t = 0; t < 4; ++t) {
        float p0 = __expf(s[qs][t][0]), p1 = __expf(s[qs][t][1]);
        float p2 = __expf(s[qs][t][2]), p3 = __expf(s[qs][t][3]);
        vsum += (p0 + p1) + (p2 + p3);
        *(unsigned*)&Pw[prow + t * 16 + quad * 4]     = pack_trunc(p0, p1);
        *(unsigned*)&Pw[prow + t * 16 + quad * 4 + 2] = pack_trunc(p2, p3);
      }
      vsum += __shfl_xor(vsum, 16, 64);
      vsum += __shfl_xor(vsum, 32, 64);
      lrun[qs] += vsum;
    }
    // ---- O^T += V^T * P^T (B-frags from wave-private LDS, no barrier) ----
    #pragma unroll
    for (int c = 0; c < 2; ++c) {
      bf16x8 bp0 = *(const bf16x8*)&Pw[(l16)*PSTRIDE + c * 32 + quad * 8];
      bf16x8 bp1 = *(const bf16x8*)&Pw[(16 + l16) * PSTRIDE + c * 32 + quad * 8];
      #pragma unroll
      for (int d = 0; d < 4; ++d) {
        o[0][d] = __builtin_amdgcn_mfma_f32_16x16x32_bf16(v.f[c * 4 + d], bp0, o[0][d], 0, 0, 0);
        o[1][d] = __builtin_amdgcn_mfma_f32_16x16x32_bf16(v.f[c * 4 + d], bp1, o[1][d], 0, 0, 0);
      }
    }
    __syncthreads();   // DMA kt+1 complete; all waves done with Kbuf[cur]
  }

  // epilogue: unnormalized partial write. Opart[ks][bh][NPAD][64] bf16, lpart[ks][bh][NPAD] fp32
  #pragma unroll
  for (int qs = 0; qs < 2; ++qs) {
    int qrow = q0 + qs * 16 + l16;
    if (qrow < N_) {
      size_t ob = (((size_t)ks * 32 + bh) * NPAD + qrow) * 64;
      #pragma unroll
      for (int d = 0; d < 4; ++d) {
        short4 st;
        st.x = f2bf(o[qs][d][0]);
        st.y = f2bf(o[qs][d][1]);
        st.z = f2bf(o[qs][d][2]);
        st.w = f2bf(o[qs][d][3]);
        *(short4*)(Opart + ob + d * 16 + quad * 4) = st;
      }
      if (quad == 0) lpart[((size_t)ks * 32 + bh) * NPAD + qrow] = lrun[qs];
    }
  }
}

// ------------- combine: attn_out = (O0+O1)/(l0+l1), bf16 -------------
__global__ __launch_bounds__(256) void combine_kernel(const short* __restrict__ Opart,
                                                      const float* __restrict__ lpart,
                                                      short* __restrict__ attn_out) {
  int idx = blockIdx.x * 256 + threadIdx.x;
  const int total = 32 * N_ * 16;          // 4 dh elems per thread
  if (idx >= total) return;
  int c4 = idx & 15;
  int t = idx >> 4;
  int n = t % N_;
  int bh = t / N_;
  int b = bh >> 4, h = bh & 15;
  const size_t halfO = (size_t)32 * NPAD * 64;
  size_t off = ((size_t)bh * NPAD + n) * 64 + c4 * 4;
  short4 a  = *(const short4*)(Opart + off);
  short4 bb = *(const short4*)(Opart + halfO + off);
  float la = lpart[(size_t)bh * NPAD + n];
  float lb = lpart[(size_t)32 * NPAD + (size_t)bh * NPAD + n];
  float inv = 1.0f / (la + lb);
  short4 st;
  st.x = f2bf((bf2f(a.x) + bf2f(bb.x)) * inv);
  st.y = f2bf((bf2f(a.y) + bf2f(bb.y)) * inv);
  st.z = f2bf((bf2f(a.z) + bf2f(bb.z)) * inv);
  st.w = f2bf((bf2f(a.w) + bf2f(bb.w)) * inv);
  size_t rowb = ((size_t)(b * N_ + n)) * (H_ * DH) + h * DH + c4 * 4;
  *(short4*)(attn_out + rowb) = st;
}

// ---------------- launcher ----------------
extern "C" void kernel_launch(void* const* d_in, const int* in_sizes, int n_in,
                              void* d_out, int out_size, void* d_ws, size_t ws_size,
                              hipStream_t stream) {
  const float* x     = (const float*)d_in[0];
  const float* gamma = (const float*)d_in[1];
  const float* beta  = (const float*)d_in[2];
  const float* w_qkv = (const float*)d_in[3];
  const float* w_out = (const float*)d_in[4];

  short* wqkvT = (short*)d_ws;                         // [3072][1024]
  short* woutT = wqkvT + (size_t)3072 * 1024;          // [1024][1024]
  short* xn    = woutT + (size_t)1024 * 1024;          // [4224][1024] (aliased as attn_out later)
  short* qkv   = xn    + (size_t)MPAD * 1024;          // [4224][3072] (aliased as Opart/lpart later)
  short* qg    = qkv   + (size_t)MPAD * 3072;          // [2][16][2112][64]
  short* kg    = qg    + (size_t)B_ * H_ * NPAD * DH;
  short* vTg   = kg    + (size_t)B_ * H_ * NPAD * DH;  // [2][16][64][2112]
  short* attn_out = xn;                                // xn dead after QKV GEMM
  // K-split partials alias qkv (dead after rope): Opart 17.3 MB bf16 + lpart 540 KB fp32 < 26 MB
  short* Opart = qkv;                                  // [2][32][2112][64] bf16
  float* lpart = (float*)(qkv + (size_t)2 * 32 * NPAD * 64);  // [2][32][2112] fp32

  ln_kernel<<<MROWS, 256, 0, stream>>>(x, gamma, beta, xn);
  transpose_cast<<<(1024 * 3072 + 255) / 256, 256, 0, stream>>>(w_qkv, wqkvT, 1024, 3072);
  transpose_cast<<<(1024 * 1024 + 255) / 256, 256, 0, stream>>>(w_out, woutT, 1024, 1024);
  {
    dim3 g(MPAD / 128, 3072 / 128);        // 33 x 24
    gemm128<unsigned short><<<g, 256, 0, stream>>>(xn, wqkvT, (unsigned short*)qkv, MROWS, 3072, 1024);
  }
  rope_kernel<<<(B_ * H_ * NPAD * 32 + 255) / 256, 256, 0, stream>>>(qkv, qg, kg, vTg);
  attn_kernel<<<8 * 4 * 17 * 2, 256, 0, stream>>>(qg, kg, vTg, Opart, lpart);   // 1088 wg
  combine_kernel<<<(32 * N_ * 16 + 255) / 256, 256, 0, stream>>>(Opart, lpart, attn_out);
  {
    dim3 g(MPAD / 128, 1024 / 128);        // 33 x 8
    gemm128<float><<<g, 256, 0, stream>>>(attn_out, woutT, (float*)d_out, MROWS, 1024, 1024);
  }
}